// Round 6
// baseline (121.324 us; speedup 1.0000x reference)
//
#include <hip/hip_runtime.h>
#include <hip/hip_bf16.h>
#include <math.h>

// VariableSelectionNetwork — MI355X (gfx950), round 6
//
// Identity: scorer LayerNorm over a size-1 axis => output == sc_ln_b, so
// softmax weights W[f] = softmax(sc_ln_b) are constant and the scorer GRN is
// dead code. Remaining: mix = x @ WT^T + c ; post-GRN (3x 256x256) ; gated
// skip ; LayerNorm(256).
//
// Round 6: back to 16 tokens/block -> grid 512 = 2 blocks/CU (round 5's 256
// blocks = 1 wave/SIMD left all latency exposed). sY LDS eliminated: LN via
// per-wave partial sums (512 B LDS), y2 kept in registers. LDS 67->17 KB,
// launch_bounds(256,2) keeps both blocks resident = 8 waves/CU.

typedef __bf16 bf16;
typedef __bf16 bf16x8 __attribute__((ext_vector_type(8)));
typedef __bf16 bf16x4 __attribute__((ext_vector_type(4)));
typedef float f32x4 __attribute__((ext_vector_type(4)));

#define NTOK 8192
#define D_   256
#define F_   32

// ws layout (bytes)
#define OFF_C      512       // 256 f32
#define OFF_WPROJT 2048      // WT[n][f] bf16 (fragment-coalesced), 16 KB
#define OFF_FC1    32768     // swizzled bf16, 128 KB each
#define OFF_FC2    163840
#define OFF_GATE   294912

// Swizzled layout: elem = j*4096 + ks*512 + lm*32 + lq*8 + e
//   == W[row = j*16+lm][col = ks*32 + lq*8 + e]; a wave's (j,ks) fragment
// load is one contiguous 1 KB segment.

// ---- prep: blocks 0..23 swizzle-convert 3 weights; block 24 softmax/WT/c ----
__global__ __launch_bounds__(256) void vsn_prep(
    const float* __restrict__ proj_w, const float* __restrict__ proj_b,
    const float* __restrict__ sc_ln_b,
    const float* __restrict__ w1, const float* __restrict__ w2,
    const float* __restrict__ w3,
    float* __restrict__ wsC, bf16* __restrict__ wsWT,
    bf16* __restrict__ o1, bf16* __restrict__ o2, bf16* __restrict__ o3)
{
  const int blk = blockIdx.x;
  if (blk < 24) {
    int g = blk * 256 + threadIdx.x;          // 0..6143
    int m = g >> 11;                          // matrix 0..2
    int c = g & 2047;                         // row = c>>3, ks = c&7
    const float* src = (m == 0) ? w1 : (m == 1) ? w2 : w3;
    bf16* dst = (m == 0) ? o1 : (m == 1) ? o2 : o3;
    int row = c >> 3, ks = c & 7;
    int j = row >> 4, lm = row & 15;
    const float* sp = src + row * 256 + ks * 32;   // 32 contig floats
    bf16* dp = dst + j * 4096 + ks * 512 + lm * 32;
    #pragma unroll
    for (int q = 0; q < 4; q++) {
      float4 a = ((const float4*)sp)[2 * q];
      float4 b = ((const float4*)sp)[2 * q + 1];
      bf16x8 v = {(bf16)a.x, (bf16)a.y, (bf16)a.z, (bf16)a.w,
                  (bf16)b.x, (bf16)b.y, (bf16)b.z, (bf16)b.w};
      *(bf16x8*)(dp + q * 8) = v;
    }
  } else {
    const int d = threadIdx.x;
    float wv[F_];
    float mx = -3.0e38f;
    #pragma unroll
    for (int f = 0; f < F_; f++) { wv[f] = sc_ln_b[f]; mx = fmaxf(mx, wv[f]); }
    float se = 0.0f;
    #pragma unroll
    for (int f = 0; f < F_; f++) { wv[f] = __expf(wv[f] - mx); se += wv[f]; }
    float inv = 1.0f / se;
    float acc = 0.0f;
    #pragma unroll
    for (int f = 0; f < F_; f++) {
      float wf = wv[f] * inv;
      acc += wf * proj_b[f * D_ + d];
      wsWT[d * F_ + f] = (bf16)(wf * proj_w[f * D_ + d]);
    }
    wsC[d] = acc;
  }
}

// ---- main: 16 tokens / 4-wave block; wave w owns cols [64w, 64w+64) ----
__global__ __launch_bounds__(256, 2) void vsn_main(
    const float* __restrict__ x,
    const float* __restrict__ wsC,
    const bf16* __restrict__ WT,
    const bf16* __restrict__ FC1, const float* __restrict__ fc1_b,
    const bf16* __restrict__ FC2, const float* __restrict__ fc2_b,
    const bf16* __restrict__ GATE, const float* __restrict__ gate_b,
    const float* __restrict__ ln_g, const float* __restrict__ ln_b,
    float* __restrict__ out)
{
  __shared__ bf16  sAct[2][16][264];   // ping-pong bf16 activations (A operand)
  __shared__ float sLN[4][16][2];      // per-wave {sum, sumsq} per token row

  const int tid  = threadIdx.x;
  const int w    = tid >> 6;
  const int lane = tid & 63;
  const int lm   = lane & 15;
  const int lq   = lane >> 4;
  const int j0   = w * 4;
  const int tok0 = blockIdx.x * 16;

  // ---- phase 1: mix = x @ WT^T + c (K=32) ----
  bf16x4 mixh[4];
  {
    const float* xp = x + (size_t)(tok0 + lm) * F_ + lq * 8;
    float4 x0 = *(const float4*)xp;
    float4 x1 = *(const float4*)(xp + 4);
    bf16x8 a0 = {(bf16)x0.x, (bf16)x0.y, (bf16)x0.z, (bf16)x0.w,
                 (bf16)x1.x, (bf16)x1.y, (bf16)x1.z, (bf16)x1.w};
    #pragma unroll
    for (int jj = 0; jj < 4; jj++) {
      int n = (j0 + jj) * 16 + lm;
      bf16x8 b = *(const bf16x8*)(WT + n * F_ + lq * 8);   // 1KB/wave contig
      float cv = wsC[n];
      f32x4 acc = {cv, cv, cv, cv};
      acc = __builtin_amdgcn_mfma_f32_16x16x32_bf16(a0, b, acc, 0, 0, 0);
      bf16x4 mh = {(bf16)acc[0], (bf16)acc[1], (bf16)acc[2], (bf16)acc[3]};
      mixh[jj] = mh;
      #pragma unroll
      for (int r = 0; r < 4; r++) sAct[0][lq * 4 + r][n] = mh[r];
    }
  }
  __syncthreads();

  // [16,256] @ W^T on this wave's 4 n-tiles; swizzled B, double-buffered
  auto gemmPhase = [&](int src, const bf16* __restrict__ W, f32x4* acc) {
    bf16x8 af[8];
    #pragma unroll
    for (int ks = 0; ks < 8; ks++)
      af[ks] = *(const bf16x8*)(&sAct[src][lm][ks * 32 + lq * 8]);
    const bf16* base = W + j0 * 4096 + lm * 32 + lq * 8;
    bf16x8 bb[8];
    #pragma unroll
    for (int ks = 0; ks < 8; ks++)
      bb[ks] = *(const bf16x8*)(base + ks * 512);          // 1KB/wave contig
    #pragma unroll
    for (int jj = 0; jj < 4; jj++) {
      bf16x8 bn[8];
      if (jj < 3) {
        const bf16* nb = base + (jj + 1) * 4096;
        #pragma unroll
        for (int ks = 0; ks < 8; ks++)
          bn[ks] = *(const bf16x8*)(nb + ks * 512);
      }
      f32x4 a = {0.f, 0.f, 0.f, 0.f};
      acc[jj] = a;
      #pragma unroll
      for (int ks = 0; ks < 8; ks++)
        acc[jj] = __builtin_amdgcn_mfma_f32_16x16x32_bf16(af[ks], bb[ks], acc[jj], 0, 0, 0);
      if (jj < 3) {
        #pragma unroll
        for (int ks = 0; ks < 8; ks++) bb[ks] = bn[ks];
      }
    }
  };

  // ---- phase 2: h1 = elu(mix @ fc1^T + b1) -> sAct[1] ----
  {
    f32x4 acc[4];
    gemmPhase(0, FC1, acc);
    #pragma unroll
    for (int jj = 0; jj < 4; jj++) {
      int n = (j0 + jj) * 16 + lm;
      float bias = fc1_b[n];
      #pragma unroll
      for (int r = 0; r < 4; r++) {
        float v = acc[jj][r] + bias;
        v = (v > 0.0f) ? v : (__expf(v) - 1.0f);
        sAct[1][lq * 4 + r][n] = (bf16)v;
      }
    }
  }
  __syncthreads();

  // ---- phase 3: h2 = h1 @ fc2^T + b2 -> sAct[0], keep packed regs ----
  bf16x4 h2h[4];
  {
    f32x4 acc[4];
    gemmPhase(1, FC2, acc);
    #pragma unroll
    for (int jj = 0; jj < 4; jj++) {
      int n = (j0 + jj) * 16 + lm;
      float bias = fc2_b[n];
      bf16x4 hh;
      #pragma unroll
      for (int r = 0; r < 4; r++) {
        hh[r] = (bf16)(acc[jj][r] + bias);
        sAct[0][lq * 4 + r][n] = hh[r];
      }
      h2h[jj] = hh;
    }
  }
  __syncthreads();

  // ---- phase 4: gate, gated skip; y2 stays in acc4 registers ----
  f32x4 acc4[4];
  gemmPhase(0, GATE, acc4);
  float rs[4] = {0.f, 0.f, 0.f, 0.f}, rq[4] = {0.f, 0.f, 0.f, 0.f};
  #pragma unroll
  for (int jj = 0; jj < 4; jj++) {
    int n = (j0 + jj) * 16 + lm;
    float bias = gate_b[n];
    #pragma unroll
    for (int r = 0; r < 4; r++) {
      float s = acc4[jj][r] + bias;
      float g = 1.0f / (1.0f + __expf(-s));
      float y = g * (float)h2h[jj][r] + (1.0f - g) * (float)mixh[jj][r];
      acc4[jj][r] = y;
      rs[r] += y;
      rq[r] += y * y;
    }
  }

  // ---- phase 5: LayerNorm(256) via cross-wave partial sums ----
  #pragma unroll
  for (int r = 0; r < 4; r++) {
    #pragma unroll
    for (int off = 1; off < 16; off <<= 1) {
      rs[r] += __shfl_xor(rs[r], off);
      rq[r] += __shfl_xor(rq[r], off);
    }
  }
  if (lm == 0) {
    #pragma unroll
    for (int r = 0; r < 4; r++) {
      sLN[w][lq * 4 + r][0] = rs[r];
      sLN[w][lq * 4 + r][1] = rq[r];
    }
  }
  __syncthreads();

  const float inv_d = 1.0f / 256.0f;
  float mean[4], rstd[4];
  #pragma unroll
  for (int r = 0; r < 4; r++) {
    int row = lq * 4 + r;
    float S = sLN[0][row][0] + sLN[1][row][0] + sLN[2][row][0] + sLN[3][row][0];
    float Q = sLN[0][row][1] + sLN[1][row][1] + sLN[2][row][1] + sLN[3][row][1];
    float m = S * inv_d;
    mean[r] = m;
    rstd[r] = rsqrtf(Q * inv_d - m * m + 1e-5f);
  }
  #pragma unroll
  for (int jj = 0; jj < 4; jj++) {
    int n = (j0 + jj) * 16 + lm;
    float lg = ln_g[n], lb = ln_b[n];
    #pragma unroll
    for (int r = 0; r < 4; r++) {
      float o = (acc4[jj][r] - mean[r]) * rstd[r] * lg + lb;
      out[(size_t)(tok0 + lq * 4 + r) * D_ + n] = o;
    }
  }
}

extern "C" void kernel_launch(void* const* d_in, const int* in_sizes, int n_in,
                              void* d_out, int out_size, void* d_ws, size_t ws_size,
                              hipStream_t stream) {
  (void)in_sizes; (void)n_in; (void)ws_size; (void)out_size;
  const float* x      = (const float*)d_in[0];
  const float* proj_w = (const float*)d_in[1];
  const float* proj_b = (const float*)d_in[2];
  const float* sclnb  = (const float*)d_in[12];
  const float* fc1w   = (const float*)d_in[13];
  const float* fc1b   = (const float*)d_in[14];
  const float* fc2w   = (const float*)d_in[15];
  const float* fc2b   = (const float*)d_in[16];
  const float* gw     = (const float*)d_in[17];
  const float* gb     = (const float*)d_in[18];
  const float* lng    = (const float*)d_in[19];
  const float* lnb    = (const float*)d_in[20];

  char* ws = (char*)d_ws;
  float* wsC   = (float*)(ws + OFF_C);
  bf16*  wsWT  = (bf16*)(ws + OFF_WPROJT);
  bf16*  bFC1  = (bf16*)(ws + OFF_FC1);
  bf16*  bFC2  = (bf16*)(ws + OFF_FC2);
  bf16*  bGATE = (bf16*)(ws + OFF_GATE);

  vsn_prep<<<25, 256, 0, stream>>>(proj_w, proj_b, sclnb, fc1w, fc2w, gw,
                                   wsC, wsWT, bFC1, bFC2, bGATE);
  vsn_main<<<NTOK / 16, 256, 0, stream>>>(x, wsC, wsWT,
                                          bFC1, fc1b, bFC2, fc2b, bGATE, gb,
                                          lng, lnb, (float*)d_out);
}